// Round 1
// baseline (3695.115 us; speedup 1.0000x reference)
//
#include <hip/hip_runtime.h>

// grid_sampler_2d_backward (bilinear, zeros padding), fp32.
// inputs: grad_output [N,C,Ho,Wo], input [N,C,H,W], grid [N,Ho,Wo,2],
//         interp_mode(=0), padding_mode(=0), align_corners(=1)
// outputs (concat in d_out): grad_input [N,C,H,W], grad_grid [N,Ho,Wo,2]

namespace {

constexpr int N = 8, C = 256, H = 96, W = 96, Ho = 96, Wo = 96;
constexpr int P = N * Ho * Wo;          // 73728 output pixels
constexpr int SPLIT = 8;                // c-chunks per pixel
constexpr int CCH = C / SPLIT;          // 32 channels per thread
constexpr int TOT = P * SPLIT;          // total threads

__global__ __launch_bounds__(256) void gs2d_bwd(
    const float* __restrict__ go, const float* __restrict__ inp,
    const float* __restrict__ grid, const int* __restrict__ acp,
    float* __restrict__ gi, float* __restrict__ gg)
{
    int g = blockIdx.x * 256 + threadIdx.x;
    if (g >= TOT) return;
    int s = g / P;                 // channel-chunk index (wave-uniform)
    int p = g - s * P;             // pixel index, wo fastest -> coalesced go loads
    int n = p / (Ho * Wo);
    int pw = p - n * (Ho * Wo);

    float2 gv = reinterpret_cast<const float2*>(grid)[p];
    float gx = gv.x, gy = gv.y;

    int ac = acp[0];               // uniform branch
    float ix, iy, sx, sy;
    if (ac) {
        sx = 0.5f * (W - 1); sy = 0.5f * (H - 1);
        ix = (gx + 1.f) * sx;        iy = (gy + 1.f) * sy;
    } else {
        sx = 0.5f * W;       sy = 0.5f * H;
        ix = (gx + 1.f) * sx - 0.5f; iy = (gy + 1.f) * sy - 0.5f;
    }
    float x0f = floorf(ix), y0f = floorf(iy);
    float wx1 = ix - x0f, wx0 = 1.f - wx1;
    float wy1 = iy - y0f, wy0 = 1.f - wy1;
    int x0 = (int)x0f, y0 = (int)y0f, x1 = x0 + 1, y1 = y0 + 1;
    bool bx0 = (x0 >= 0) & (x0 < W), bx1 = (x1 >= 0) & (x1 < W);
    bool by0 = (y0 >= 0) & (y0 < H), by1 = (y1 >= 0) & (y1 < H);
    bool m00 = bx0 & by0, m01 = bx1 & by0, m10 = bx0 & by1, m11 = bx1 & by1;
    int x0c = min(max(x0, 0), W - 1), x1c = min(max(x1, 0), W - 1);
    int y0c = min(max(y0, 0), H - 1), y1c = min(max(y1, 0), H - 1);
    int o00 = y0c * W + x0c, o01 = y0c * W + x1c;
    int o10 = y1c * W + x0c, o11 = y1c * W + x1c;

    float w00 = wy0 * wx0, w01 = wy0 * wx1, w10 = wy1 * wx0, w11 = wy1 * wx1;

    long cbase = (long)n * C + s * CCH;
    const float* gop = go  + cbase * (Ho * Wo) + pw;
    const float* ipp = inp + cbase * (H * W);
    float*       gip = gi  + cbase * (H * W);

    float gix = 0.f, giy = 0.f;
    #pragma unroll 4
    for (int c = 0; c < CCH; ++c) {
        float g0 = gop[c * (Ho * Wo)];
        const float* ipc = ipp + c * (H * W);
        float*       gic = gip + c * (H * W);
        float v00 = m00 ? ipc[o00] : 0.f;
        float v01 = m01 ? ipc[o01] : 0.f;
        float v10 = m10 ? ipc[o10] : 0.f;
        float v11 = m11 ? ipc[o11] : 0.f;
        if (m00) atomicAdd(gic + o00, g0 * w00);
        if (m01) atomicAdd(gic + o01, g0 * w01);
        if (m10) atomicAdd(gic + o10, g0 * w10);
        if (m11) atomicAdd(gic + o11, g0 * w11);
        gix += g0 * (wy0 * (v01 - v00) + wy1 * (v11 - v10));
        giy += g0 * (wx0 * (v10 - v00) + wx1 * (v11 - v01));
    }
    atomicAdd(&gg[2 * p],     gix * sx);
    atomicAdd(&gg[2 * p + 1], giy * sy);
}

} // namespace

extern "C" void kernel_launch(void* const* d_in, const int* in_sizes, int n_in,
                              void* d_out, int out_size, void* d_ws, size_t ws_size,
                              hipStream_t stream) {
    const float* go   = (const float*)d_in[0];
    const float* inp  = (const float*)d_in[1];
    const float* grid = (const float*)d_in[2];
    const int*   acp  = (const int*)d_in[5];
    float* gi = (float*)d_out;
    float* gg = gi + (size_t)N * C * H * W;

    // zero both outputs (grad_input is scatter-add, grad_grid is atomic-accumulated)
    hipMemsetAsync(d_out, 0, (size_t)out_size * sizeof(float), stream);

    int blocks = (TOT + 255) / 256;
    gs2d_bwd<<<blocks, 256, 0, stream>>>(go, inp, grid, acp, gi, gg);
}

// Round 2
// 484.402 us; speedup vs baseline: 7.6282x; 7.6282x over previous
//
#include <hip/hip_runtime.h>

// grid_sampler_2d_backward (bilinear, zeros padding), fp32, NHWC strategy.
// inputs: grad_output [N,C,Ho,Wo], input [N,C,H,W], grid [N,Ho,Wo,2], modes.
// outputs (concat in d_out): grad_input [N,C,H,W], grad_grid [N,Ho,Wo,2]
//
// Plan: T1: go -> goT [N,HoWo,C]; T2: inp -> inpT [N,HW,C]; main kernel with
// lane=channel (coalesced gathers AND coalesced atomics into giT [N,HW,C],
// grad_grid via shfl+LDS reduce, direct store); T3: giT -> grad_input NCHW.

namespace {

constexpr int N = 8, C = 256, H = 96, W = 96, Ho = 96, Wo = 96;
constexpr int S = H * W;                  // 9216 (== Ho*Wo)
constexpr long GI = (long)N * C * S;      // 18.9M elements
constexpr int P = N * Ho * Wo;            // 73728 pixels
constexpr int PPB = 4;                    // pixels per block (main kernel)

// ---- tiled batched transpose: src [B][rows][cols] -> dst [B][cols][rows] ----
__global__ __launch_bounds__(256) void transpose_k(
    const float* __restrict__ src, float* __restrict__ dst, int rows, int cols)
{
    __shared__ float t[32][33];
    long b = blockIdx.z;
    src += b * (long)rows * cols;
    dst += b * (long)rows * cols;
    int c0 = blockIdx.x * 32, r0 = blockIdx.y * 32;
    int x = threadIdx.x, y = threadIdx.y;          // 32 x 8
    #pragma unroll
    for (int j = 0; j < 4; ++j)
        t[y + 8 * j][x] = src[(long)(r0 + y + 8 * j) * cols + c0 + x];
    __syncthreads();
    #pragma unroll
    for (int j = 0; j < 4; ++j)
        dst[(long)(c0 + y + 8 * j) * rows + r0 + x] = t[x][y + 8 * j];
}

// ---- main: lane = channel; coalesced gathers + coalesced atomics ----
__global__ __launch_bounds__(256) void gs2d_bwd_nhwc(
    const float* __restrict__ goT, const float* __restrict__ inpT,
    const float* __restrict__ grid, const int* __restrict__ acp,
    float* __restrict__ giT, float* __restrict__ gg)
{
    __shared__ float red[PPB][4][2];
    int c = threadIdx.x;                  // channel 0..255
    int wid = c >> 6, lane = c & 63;
    int ac = acp[0];

    for (int i = 0; i < PPB; ++i) {
        int p = blockIdx.x * PPB + i;
        int n = p / S; int pw = p - n * S;
        float gx = grid[2 * p], gy = grid[2 * p + 1];
        float sx, sy, ix, iy;
        if (ac) { sx = 0.5f * (W - 1); sy = 0.5f * (H - 1);
                  ix = (gx + 1.f) * sx;          iy = (gy + 1.f) * sy; }
        else    { sx = 0.5f * W;       sy = 0.5f * H;
                  ix = (gx + 1.f) * sx - 0.5f;   iy = (gy + 1.f) * sy - 0.5f; }
        float x0f = floorf(ix), y0f = floorf(iy);
        float wx1 = ix - x0f, wx0 = 1.f - wx1;
        float wy1 = iy - y0f, wy0 = 1.f - wy1;
        int x0 = (int)x0f, y0 = (int)y0f, x1 = x0 + 1, y1 = y0 + 1;
        bool bx0 = (x0 >= 0) & (x0 < W), bx1 = (x1 >= 0) & (x1 < W);
        bool by0 = (y0 >= 0) & (y0 < H), by1 = (y1 >= 0) & (y1 < H);
        bool m00 = bx0 & by0, m01 = bx1 & by0, m10 = bx0 & by1, m11 = bx1 & by1;
        int x0c = min(max(x0, 0), W - 1), x1c = min(max(x1, 0), W - 1);
        int y0c = min(max(y0, 0), H - 1), y1c = min(max(y1, 0), H - 1);
        long nb = (long)n * S;
        long a00 = (nb + y0c * W + x0c) * (long)C + c;
        long a01 = (nb + y0c * W + x1c) * (long)C + c;
        long a10 = (nb + y1c * W + x0c) * (long)C + c;
        long a11 = (nb + y1c * W + x1c) * (long)C + c;

        float g0 = goT[(nb + pw) * (long)C + c];
        float v00 = m00 ? inpT[a00] : 0.f;
        float v01 = m01 ? inpT[a01] : 0.f;
        float v10 = m10 ? inpT[a10] : 0.f;
        float v11 = m11 ? inpT[a11] : 0.f;

        float w00 = wy0 * wx0, w01 = wy0 * wx1, w10 = wy1 * wx0, w11 = wy1 * wx1;
        if (m00) atomicAdd(&giT[a00], g0 * w00);
        if (m01) atomicAdd(&giT[a01], g0 * w01);
        if (m10) atomicAdd(&giT[a10], g0 * w10);
        if (m11) atomicAdd(&giT[a11], g0 * w11);

        float gix = g0 * (wy0 * (v01 - v00) + wy1 * (v11 - v10));
        float giy = g0 * (wx0 * (v10 - v00) + wx1 * (v11 - v01));
        #pragma unroll
        for (int m = 32; m >= 1; m >>= 1) {
            gix += __shfl_xor(gix, m, 64);
            giy += __shfl_xor(giy, m, 64);
        }
        if (lane == 0) { red[i][wid][0] = gix; red[i][wid][1] = giy; }
    }
    __syncthreads();
    if (c < PPB * 2) {
        int i = c >> 1, d = c & 1;
        float s = red[i][0][d] + red[i][1][d] + red[i][2][d] + red[i][3][d];
        int p = blockIdx.x * PPB + i;
        float sc;
        if (ac) sc = d ? 0.5f * (H - 1) : 0.5f * (W - 1);
        else    sc = d ? 0.5f * H       : 0.5f * W;
        gg[2 * p + d] = s * sc;
    }
}

// ---- fallback (round-1 kernel) if workspace too small ----
constexpr int SPLIT = 8, CCH = C / SPLIT, TOT = P * SPLIT;

__global__ __launch_bounds__(256) void gs2d_bwd_fallback(
    const float* __restrict__ go, const float* __restrict__ inp,
    const float* __restrict__ grid, const int* __restrict__ acp,
    float* __restrict__ gi, float* __restrict__ gg)
{
    int g = blockIdx.x * 256 + threadIdx.x;
    if (g >= TOT) return;
    int s = g / P;
    int p = g - s * P;
    int n = p / (Ho * Wo);
    int pw = p - n * (Ho * Wo);
    float2 gv = reinterpret_cast<const float2*>(grid)[p];
    float gx = gv.x, gy = gv.y;
    int ac = acp[0];
    float ix, iy, sx, sy;
    if (ac) { sx = 0.5f * (W - 1); sy = 0.5f * (H - 1);
              ix = (gx + 1.f) * sx;        iy = (gy + 1.f) * sy; }
    else    { sx = 0.5f * W; sy = 0.5f * H;
              ix = (gx + 1.f) * sx - 0.5f; iy = (gy + 1.f) * sy - 0.5f; }
    float x0f = floorf(ix), y0f = floorf(iy);
    float wx1 = ix - x0f, wx0 = 1.f - wx1;
    float wy1 = iy - y0f, wy0 = 1.f - wy1;
    int x0 = (int)x0f, y0 = (int)y0f, x1 = x0 + 1, y1 = y0 + 1;
    bool bx0 = (x0 >= 0) & (x0 < W), bx1 = (x1 >= 0) & (x1 < W);
    bool by0 = (y0 >= 0) & (y0 < H), by1 = (y1 >= 0) & (y1 < H);
    bool m00 = bx0 & by0, m01 = bx1 & by0, m10 = bx0 & by1, m11 = bx1 & by1;
    int x0c = min(max(x0, 0), W - 1), x1c = min(max(x1, 0), W - 1);
    int y0c = min(max(y0, 0), H - 1), y1c = min(max(y1, 0), H - 1);
    int o00 = y0c * W + x0c, o01 = y0c * W + x1c;
    int o10 = y1c * W + x0c, o11 = y1c * W + x1c;
    float w00 = wy0 * wx0, w01 = wy0 * wx1, w10 = wy1 * wx0, w11 = wy1 * wx1;
    long cbase = (long)n * C + s * CCH;
    const float* gop = go  + cbase * (Ho * Wo) + pw;
    const float* ipp = inp + cbase * (H * W);
    float*       gip = gi  + cbase * (H * W);
    float gix = 0.f, giy = 0.f;
    #pragma unroll 4
    for (int cc = 0; cc < CCH; ++cc) {
        float g0 = gop[cc * (Ho * Wo)];
        const float* ipc = ipp + cc * (H * W);
        float*       gic = gip + cc * (H * W);
        float v00 = m00 ? ipc[o00] : 0.f;
        float v01 = m01 ? ipc[o01] : 0.f;
        float v10 = m10 ? ipc[o10] : 0.f;
        float v11 = m11 ? ipc[o11] : 0.f;
        if (m00) atomicAdd(gic + o00, g0 * w00);
        if (m01) atomicAdd(gic + o01, g0 * w01);
        if (m10) atomicAdd(gic + o10, g0 * w10);
        if (m11) atomicAdd(gic + o11, g0 * w11);
        gix += g0 * (wy0 * (v01 - v00) + wy1 * (v11 - v10));
        giy += g0 * (wx0 * (v10 - v00) + wx1 * (v11 - v01));
    }
    atomicAdd(&gg[2 * p],     gix * sx);
    atomicAdd(&gg[2 * p + 1], giy * sy);
}

} // namespace

extern "C" void kernel_launch(void* const* d_in, const int* in_sizes, int n_in,
                              void* d_out, int out_size, void* d_ws, size_t ws_size,
                              hipStream_t stream) {
    const float* go   = (const float*)d_in[0];
    const float* inp  = (const float*)d_in[1];
    const float* grid = (const float*)d_in[2];
    const int*   acp  = (const int*)d_in[5];
    float* gi = (float*)d_out;
    float* gg = gi + GI;

    size_t need = 3 * (size_t)GI * sizeof(float);
    if (ws_size >= need) {
        float* goT  = (float*)d_ws;
        float* inpT = goT + GI;
        float* giT  = inpT + GI;
        // T1/T2: NCHW -> NHWC ([C][S] -> [S][C] per n)
        transpose_k<<<dim3(S / 32, C / 32, N), dim3(32, 8), 0, stream>>>(go,  goT,  C, S);
        transpose_k<<<dim3(S / 32, C / 32, N), dim3(32, 8), 0, stream>>>(inp, inpT, C, S);
        hipMemsetAsync(giT, 0, (size_t)GI * sizeof(float), stream);
        gs2d_bwd_nhwc<<<P / PPB, 256, 0, stream>>>(goT, inpT, grid, acp, giT, gg);
        // T3: NHWC -> NCHW ([S][C] -> [C][S] per n); writes every gi element
        transpose_k<<<dim3(C / 32, S / 32, N), dim3(32, 8), 0, stream>>>(giT, gi, S, C);
    } else {
        hipMemsetAsync(d_out, 0, (size_t)out_size * sizeof(float), stream);
        gs2d_bwd_fallback<<<(TOT + 255) / 256, 256, 0, stream>>>(go, inp, grid, acp, gi, gg);
    }
}

// Round 3
// 396.309 us; speedup vs baseline: 9.3238x; 1.2223x over previous
//
#include <hip/hip_runtime.h>

// grid_sampler_2d_backward (bilinear, zeros, fp32) — gather strategy, no fp32 atomics.
// Pipeline:
//   memset cnt (295 KB)
//   T:  go -> goT [N,S,C], inp -> inpT [N,S,C]   (fused float4 transpose)
//   A:  per-pixel: grad_grid (shfl reduce, direct store) + bin fill {pw,w} per valid corner
//   B:  per-cell gather: gi[n,c,cell] = sum_e w_e * goT[n,pw_e,c]; NCHW write via LDS

namespace {

constexpr int N = 8, C = 256, H = 96, W = 96, Ho = 96, Wo = 96;
constexpr int S = H * W;                    // 9216
constexpr long GI = (long)N * C * S;
constexpr int P = N * Ho * Wo;              // 73728
constexpr int NS = N * S;                   // 73728 bins
constexpr int CAP = 32;                     // entries per bin (mean 4, Poisson)
constexpr int PPB = 4;

struct Ent { int pw; float w; };

// ---- fused 64x64 float4 transpose: z<N: go->goT ; z>=N: inp->inpT ----
// src [C][S] -> dst [S][C] per batch
__global__ __launch_bounds__(256) void transpose2_k(
    const float* __restrict__ go, const float* __restrict__ inp,
    float* __restrict__ goT, float* __restrict__ inpT)
{
    __shared__ float t[64][68];
    int z = blockIdx.z;
    const float* src = (z < N ? go : inp) + (long)(z < N ? z : z - N) * C * S;
    float* dst       = (z < N ? goT : inpT) + (long)(z < N ? z : z - N) * C * S;
    int c0 = blockIdx.x * 64;                // col tile (S dim)
    int r0 = blockIdx.y * 64;                // row tile (C dim)
    int tx = threadIdx.x & 15, ty = threadIdx.x >> 4;   // 16 x 16
    #pragma unroll
    for (int j = 0; j < 4; ++j) {
        int row = ty + 16 * j;
        float4 v = *reinterpret_cast<const float4*>(&src[(long)(r0 + row) * S + c0 + 4 * tx]);
        t[row][4 * tx + 0] = v.x; t[row][4 * tx + 1] = v.y;
        t[row][4 * tx + 2] = v.z; t[row][4 * tx + 3] = v.w;
    }
    __syncthreads();
    #pragma unroll
    for (int j = 0; j < 4; ++j) {
        int crow = ty + 16 * j;              // S-index within tile
        float4 u;
        u.x = t[4 * tx + 0][crow]; u.y = t[4 * tx + 1][crow];
        u.z = t[4 * tx + 2][crow]; u.w = t[4 * tx + 3][crow];
        *reinterpret_cast<float4*>(&dst[(long)(c0 + crow) * C + r0 + 4 * tx]) = u;
    }
}

// ---- A: grad_grid + bin fill ----
__global__ __launch_bounds__(256) void gs2d_grid_fill(
    const float* __restrict__ goT, const float* __restrict__ inpT,
    const float* __restrict__ grid, const int* __restrict__ acp,
    float* __restrict__ gg, int* __restrict__ cnt, Ent* __restrict__ ents)
{
    __shared__ float red[PPB][4][2];
    int c = threadIdx.x;
    int wid = c >> 6, lane = c & 63;
    int ac = acp[0];

    for (int i = 0; i < PPB; ++i) {
        int p = blockIdx.x * PPB + i;
        int n = p / S; int pw = p - n * S;
        float gx = grid[2 * p], gy = grid[2 * p + 1];
        float sx, sy, ix, iy;
        if (ac) { sx = 0.5f * (W - 1); sy = 0.5f * (H - 1);
                  ix = (gx + 1.f) * sx;          iy = (gy + 1.f) * sy; }
        else    { sx = 0.5f * W;       sy = 0.5f * H;
                  ix = (gx + 1.f) * sx - 0.5f;   iy = (gy + 1.f) * sy - 0.5f; }
        float x0f = floorf(ix), y0f = floorf(iy);
        float wx1 = ix - x0f, wx0 = 1.f - wx1;
        float wy1 = iy - y0f, wy0 = 1.f - wy1;
        int x0 = (int)x0f, y0 = (int)y0f, x1 = x0 + 1, y1 = y0 + 1;
        bool bx0 = (x0 >= 0) & (x0 < W), bx1 = (x1 >= 0) & (x1 < W);
        bool by0 = (y0 >= 0) & (y0 < H), by1 = (y1 >= 0) & (y1 < H);
        bool m00 = bx0 & by0, m01 = bx1 & by0, m10 = bx0 & by1, m11 = bx1 & by1;
        int x0c = min(max(x0, 0), W - 1), x1c = min(max(x1, 0), W - 1);
        int y0c = min(max(y0, 0), H - 1), y1c = min(max(y1, 0), H - 1);
        int o00 = y0c * W + x0c, o01 = y0c * W + x1c;
        int o10 = y1c * W + x0c, o11 = y1c * W + x1c;
        long nb = (long)n * S;

        float g0 = goT[(nb + pw) * (long)C + c];
        float v00 = m00 ? inpT[(nb + o00) * (long)C + c] : 0.f;
        float v01 = m01 ? inpT[(nb + o01) * (long)C + c] : 0.f;
        float v10 = m10 ? inpT[(nb + o10) * (long)C + c] : 0.f;
        float v11 = m11 ? inpT[(nb + o11) * (long)C + c] : 0.f;

        float gix = g0 * (wy0 * (v01 - v00) + wy1 * (v11 - v10));
        float giy = g0 * (wx0 * (v10 - v00) + wx1 * (v11 - v01));
        #pragma unroll
        for (int m = 32; m >= 1; m >>= 1) {
            gix += __shfl_xor(gix, m, 64);
            giy += __shfl_xor(giy, m, 64);
        }
        if (lane == 0) { red[i][wid][0] = gix; red[i][wid][1] = giy; }

        // bin fill: threads 0..3 handle one corner each
        if (c < 4) {
            bool mm  = (c == 0) ? m00 : (c == 1) ? m01 : (c == 2) ? m10 : m11;
            int  oo  = (c == 0) ? o00 : (c == 1) ? o01 : (c == 2) ? o10 : o11;
            float ww = (c == 0) ? wy0 * wx0 : (c == 1) ? wy0 * wx1
                     : (c == 2) ? wy1 * wx0 : wy1 * wx1;
            if (mm) {
                int b = (int)nb + oo;
                int idx = atomicAdd(&cnt[b], 1);
                if (idx < CAP) { Ent e; e.pw = pw; e.w = ww; ents[(long)b * CAP + idx] = e; }
            }
        }
    }
    __syncthreads();
    if (c < PPB * 2) {
        int i = c >> 1, d = c & 1;
        float s = red[i][0][d] + red[i][1][d] + red[i][2][d] + red[i][3][d];
        int p = blockIdx.x * PPB + i;
        float sc;
        if (ac) sc = d ? 0.5f * (H - 1) : 0.5f * (W - 1);
        else    sc = d ? 0.5f * H       : 0.5f * W;
        gg[2 * p + d] = s * sc;
    }
}

// ---- B: gather grad_input, write NCHW directly ----
__global__ __launch_bounds__(256) void gs2d_gather(
    const float* __restrict__ goT, const int* __restrict__ cnt,
    const Ent* __restrict__ ents, float* __restrict__ gi)
{
    __shared__ float lds[256][33];
    int tile = blockIdx.x;                   // 2304 tiles of 32 cells
    int n = tile / (S / 32);
    int c0 = (tile - n * (S / 32)) * 32;     // first cell in tile
    int ch = threadIdx.x;                    // channel 0..255
    const float* goTn = goT + (long)n * S * C;

    float acc[32];
    #pragma unroll
    for (int i = 0; i < 32; ++i) {
        int b = n * S + c0 + i;
        int m = min(cnt[b], CAP);
        const Ent* el = ents + (long)b * CAP;
        float a = 0.f;
        for (int e = 0; e < m; ++e) {
            Ent en = el[e];
            a += en.w * goTn[(long)en.pw * C + ch];
        }
        acc[i] = a;
    }
    #pragma unroll
    for (int i = 0; i < 32; ++i) lds[ch][i] = acc[i];
    __syncthreads();
    // NCHW write: 256ch x 32 cells, coalesced rows of 128B
    #pragma unroll
    for (int k = 0; k < 32; ++k) {
        int idx = k * 256 + threadIdx.x;
        int cc = idx >> 5, pos = idx & 31;
        gi[((long)n * C + cc) * S + c0 + pos] = lds[cc][pos];
    }
}

// ---- fallback (round-1) ----
constexpr int SPLIT = 8, CCH = C / SPLIT, TOT = P * SPLIT;
__global__ __launch_bounds__(256) void gs2d_bwd_fallback(
    const float* __restrict__ go, const float* __restrict__ inp,
    const float* __restrict__ grid, const int* __restrict__ acp,
    float* __restrict__ gi, float* __restrict__ gg)
{
    int g = blockIdx.x * 256 + threadIdx.x;
    if (g >= TOT) return;
    int s = g / P;
    int p = g - s * P;
    int n = p / (Ho * Wo);
    int pw = p - n * (Ho * Wo);
    float2 gv = reinterpret_cast<const float2*>(grid)[p];
    float gx = gv.x, gy = gv.y;
    int ac = acp[0];
    float ix, iy, sx, sy;
    if (ac) { sx = 0.5f * (W - 1); sy = 0.5f * (H - 1);
              ix = (gx + 1.f) * sx;        iy = (gy + 1.f) * sy; }
    else    { sx = 0.5f * W; sy = 0.5f * H;
              ix = (gx + 1.f) * sx - 0.5f; iy = (gy + 1.f) * sy - 0.5f; }
    float x0f = floorf(ix), y0f = floorf(iy);
    float wx1 = ix - x0f, wx0 = 1.f - wx1;
    float wy1 = iy - y0f, wy0 = 1.f - wy1;
    int x0 = (int)x0f, y0 = (int)y0f, x1 = x0 + 1, y1 = y0 + 1;
    bool bx0 = (x0 >= 0) & (x0 < W), bx1 = (x1 >= 0) & (x1 < W);
    bool by0 = (y0 >= 0) & (y0 < H), by1 = (y1 >= 0) & (y1 < H);
    bool m00 = bx0 & by0, m01 = bx1 & by0, m10 = bx0 & by1, m11 = bx1 & by1;
    int x0c = min(max(x0, 0), W - 1), x1c = min(max(x1, 0), W - 1);
    int y0c = min(max(y0, 0), H - 1), y1c = min(max(y1, 0), H - 1);
    int o00 = y0c * W + x0c, o01 = y0c * W + x1c;
    int o10 = y1c * W + x0c, o11 = y1c * W + x1c;
    float w00 = wy0 * wx0, w01 = wy0 * wx1, w10 = wy1 * wx0, w11 = wy1 * wx1;
    long cbase = (long)n * C + s * CCH;
    const float* gop = go  + cbase * (Ho * Wo) + pw;
    const float* ipp = inp + cbase * (H * W);
    float*       gip = gi  + cbase * (H * W);
    float gix = 0.f, giy = 0.f;
    #pragma unroll 4
    for (int cc = 0; cc < CCH; ++cc) {
        float g0 = gop[cc * (Ho * Wo)];
        const float* ipc = ipp + cc * (H * W);
        float*       gic = gip + cc * (H * W);
        float v00 = m00 ? ipc[o00] : 0.f;
        float v01 = m01 ? ipc[o01] : 0.f;
        float v10 = m10 ? ipc[o10] : 0.f;
        float v11 = m11 ? ipc[o11] : 0.f;
        if (m00) atomicAdd(gic + o00, g0 * w00);
        if (m01) atomicAdd(gic + o01, g0 * w01);
        if (m10) atomicAdd(gic + o10, g0 * w10);
        if (m11) atomicAdd(gic + o11, g0 * w11);
        gix += g0 * (wy0 * (v01 - v00) + wy1 * (v11 - v10));
        giy += g0 * (wx0 * (v10 - v00) + wx1 * (v11 - v01));
    }
    atomicAdd(&gg[2 * p],     gix * sx);
    atomicAdd(&gg[2 * p + 1], giy * sy);
}

} // namespace

extern "C" void kernel_launch(void* const* d_in, const int* in_sizes, int n_in,
                              void* d_out, int out_size, void* d_ws, size_t ws_size,
                              hipStream_t stream) {
    const float* go   = (const float*)d_in[0];
    const float* inp  = (const float*)d_in[1];
    const float* grid = (const float*)d_in[2];
    const int*   acp  = (const int*)d_in[5];
    float* gi = (float*)d_out;
    float* gg = gi + GI;

    size_t need = 2 * (size_t)GI * sizeof(float) + (size_t)NS * sizeof(int)
                + (size_t)NS * CAP * sizeof(Ent);
    if (ws_size >= need) {
        float* goT  = (float*)d_ws;
        float* inpT = goT + GI;
        int*   cnt  = (int*)(inpT + GI);
        Ent*   ents = (Ent*)(cnt + NS);

        hipMemsetAsync(cnt, 0, (size_t)NS * sizeof(int), stream);
        transpose2_k<<<dim3(S / 64, C / 64, 2 * N), 256, 0, stream>>>(go, inp, goT, inpT);
        gs2d_grid_fill<<<P / PPB, 256, 0, stream>>>(goT, inpT, grid, acp, gg, cnt, ents);
        gs2d_gather<<<NS / 32, 256, 0, stream>>>(goT, cnt, ents, gi);
    } else {
        hipMemsetAsync(d_out, 0, (size_t)out_size * sizeof(float), stream);
        gs2d_bwd_fallback<<<(TOT + 255) / 256, 256, 0, stream>>>(go, inp, grid, acp, gi, gg);
    }
}